// Round 10
// baseline (171.535 us; speedup 1.0000x reference)
//
#include <hip/hip_runtime.h>
#include <math.h>

#define TPB 256
#define FSCALE 32768.0f            // 2^15 fixed-point for fx/fy
#define INV_FSCALE (1.0f / 32768.0f)
#define FBIAS (1 << 19)            // per-add bias keeps packed fields positive

// ctrl (floats): [0:64) bn1 sum, [64:128) bn1 sumsq, [128:160) bn2 sum,
// [160:192) bn2 sumsq, int counters at [192] and [208] (separate cachelines).

// -------------------- pool: LDS int bins, 2 u64 atomics/pixel (round-7 proven) ----
__global__ void pool_kernel(const int* __restrict__ labels,
                            const float* __restrict__ fx,
                            const float* __restrict__ fy,
                            float* __restrict__ partial,
                            float* __restrict__ ctrl,
                            int K, int H, int W, int wlog, int chunks) {
    extern __shared__ unsigned long long sh[];   // geo[K] | fxy[K]
    unsigned long long* geo = sh;
    unsigned long long* fxy = sh + K;
    const int tid = threadIdx.x;

    if (blockIdx.x == 0 && tid < 224) ctrl[tid] = 0.f;   // stats + barrier counters

    for (int i = tid; i < K; i += TPB) { geo[i] = 0ull; fxy[i] = 0ull; }
    __syncthreads();

    const int P = H * W;
    const int b = blockIdx.x / chunks;
    const int chunk = blockIdx.x - b * chunks;
    const int chunkP = P / chunks;
    const size_t base = (size_t)b * P + (size_t)chunk * chunkP;
    const int4*   l4p  = (const int4*)(labels + base);
    const float4* fx4p = (const float4*)(fx + base);
    const float4* fy4p = (const float4*)(fy + base);
    const int nvec = chunkP >> 2;

    for (int v = tid; v < nvec; v += TPB) {
        int4   l4 = l4p[v];
        float4 f4 = fx4p[v];
        float4 g4 = fy4p[v];
        int p0 = chunk * chunkP + (v << 2);
        int   ls[4] = {l4.x, l4.y, l4.z, l4.w};
        float fs[4] = {f4.x, f4.y, f4.z, f4.w};
        float gs[4] = {g4.x, g4.y, g4.z, g4.w};
        #pragma unroll
        for (int s = 0; s < 4; ++s) {
            int p = p0 + s;
            int i, j;
            if (wlog >= 0) { i = p >> wlog; j = p & (W - 1); }
            else           { i = p / W;     j = p - i * W; }
            unsigned long long gadd = ((unsigned long long)i << 40)
                                    | ((unsigned long long)j << 16) | 1ull;
            int qx = __float2int_rn(fminf(fmaxf(fs[s], -15.f), 15.f) * FSCALE) + FBIAS;
            int qy = __float2int_rn(fminf(fmaxf(gs[s], -15.f), 15.f) * FSCALE) + FBIAS;
            unsigned long long fadd = ((unsigned long long)(unsigned int)qx << 32)
                                    | (unsigned long long)(unsigned int)qy;
            atomicAdd(&geo[ls[s]], gadd);
            atomicAdd(&fxy[ls[s]], fadd);
        }
    }
    __syncthreads();

    const float sx = 2.f / (float)(H - 1);           // xx varies along dim 2 (i)
    const float sy = 2.f / (float)(W - 1);           // yy varies along dim 3 (j)
    float* outp = partial + (size_t)blockIdx.x * K * 5;
    for (int k = tid; k < K; k += TPB) {
        unsigned long long g = geo[k];
        unsigned long long ff = fxy[k];
        unsigned int ci = (unsigned int)(g & 0xFFFFull);
        float cnt = (float)ci;
        float sj  = (float)(unsigned int)((g >> 16) & 0xFFFFFFull);
        float si  = (float)(unsigned int)(g >> 40);
        long long cbias = (long long)ci << 19;
        float* p = outp + k * 5;
        p[0] = (float)((long long)(ff >> 32) - cbias) * INV_FSCALE;           // sum fx
        p[1] = (float)((long long)(ff & 0xFFFFFFFFull) - cbias) * INV_FSCALE; // sum fy
        p[2] = sx * si - cnt;                        // sum xx
        p[3] = sy * sj - cnt;                        // sum yy
        p[4] = cnt;                                  // count
    }
}

// -------------------- grid barrier: release arrival, relaxed polls, one acquire --
// Round-8 (correct, slow): ACQUIRE per poll -> L1+XCD-L2 invalidate per iteration;
// early blocks storm-invalidate L2 while laggards still stream `partial`.
// Round-9 (fast, WRONG): fully relaxed -> stats atomicAdds not yet visible when
// counter bump lands (vmcnt signals issue, not visibility) and readers can hold
// stale ctrl lines. This version: RELEASE arrival (one wbl2/block) + RELAXED
// polls (agent-scope atomic loads are performed at the coherent point -> always
// observe the counter; round 9 proved no livelock) + ONE ACQUIRE after the loop
// (single L1/L2 inv per block; block shares one CU's L1, so lane-0 acquire +
// __syncthreads orders all threads' stats reads — validated by round 8 passing).
__device__ __forceinline__ void grid_sync(int* cnt, int nblk) {
    __syncthreads();
    if (threadIdx.x == 0) {
        __hip_atomic_fetch_add(cnt, 1, __ATOMIC_RELEASE, __HIP_MEMORY_SCOPE_AGENT);
        while (__hip_atomic_load(cnt, __ATOMIC_RELAXED, __HIP_MEMORY_SCOPE_AGENT) < nblk)
            __builtin_amdgcn_s_sleep(8);
        __hip_atomic_load(cnt, __ATOMIC_ACQUIRE, __HIP_MEMORY_SCOPE_AGENT);
    }
    __syncthreads();
}

// -------------------- K2: reduce+layer1 | bn1+layer2 | bn2+normalize -------------
// 256 blocks x 256 threads; block owns 64 tokens; h1/h2 live in LDS only.
__global__ __launch_bounds__(TPB)
void fused234_kernel(const float* __restrict__ partial,
                     const int* __restrict__ frame_idx,
                     const int* __restrict__ n_frames_p,
                     const float* __restrict__ conv_w,
                     const float* __restrict__ conv_b,
                     const float* __restrict__ bn1_g,
                     const float* __restrict__ bn1_b,
                     const float* __restrict__ lin_w,
                     const float* __restrict__ lin_b,
                     const float* __restrict__ bn2_g,
                     const float* __restrict__ bn2_b,
                     float* __restrict__ ctrl,
                     float* __restrict__ out,
                     int K, int N, int chunks) {
    __shared__ float red[320], feat[320], cw[320], cb[64];
    __shared__ float h1t[64 * 64];                   // [c][tt]
    __shared__ float w2[2048], lb[32];
    __shared__ float sc1[64], sh1[64], sc2[32], sh2[32];
    __shared__ float h2t[32 * 65];                   // [o][tt], padded
    __shared__ float ssqp[4 * 64], linv[64];

    const int tid = threadIdx.x;
    const int nblk = gridDim.x;
    int* cnt0 = (int*)(ctrl + 192);
    int* cnt1 = (int*)(ctrl + 208);

    // stage weights (overlaps phase A loads)
    for (int i = tid; i < 320; i += TPB) cw[i] = conv_w[i];
    if (tid < 64) cb[tid] = conv_b[tid];
    for (int i = tid; i < 2048; i += TPB) w2[i] = lin_w[i];
    if (tid < 32) lb[tid] = lin_b[tid];

    // ---------- phase A: reduce slabs + mean + layer1 (LDS) + bn1 stats ----------
    const int t0 = blockIdx.x * 64;
    const int b  = t0 / K;                           // 64 | K -> one batch per block
    const int k0 = t0 - b * K;

    float acc0 = 0.f, acc1 = 0.f;
    const float* pb = partial + ((size_t)b * chunks * K + k0) * 5;
    for (int ch = 0; ch < chunks; ++ch) {
        const float* pc = pb + (size_t)ch * K * 5;
        acc0 += pc[tid];
        if (tid < 64) acc1 += pc[256 + tid];
    }
    red[tid] = acc0;
    if (tid < 64) red[256 + tid] = acc1;
    __syncthreads();

    const int g  = tid >> 6;
    const int tt = tid & 63;
    const int t  = t0 + tt;
    const bool valid = t < N;
    if (g == 0) {
        const float* r = red + tt * 5;
        float inv = 1.f / fmaxf(r[4], 1.f);
        float invnf = 1.f / (float)(n_frames_p[0] - 1);
        feat[tt * 5 + 0] = valid ? (float)frame_idx[b] * invnf : 0.f;
        feat[tt * 5 + 1] = r[0] * inv;
        feat[tt * 5 + 2] = r[1] * inv;
        feat[tt * 5 + 3] = r[2] * inv;
        feat[tt * 5 + 4] = r[3] * inv;
    }
    __syncthreads();

    {
        const float x0 = feat[tt * 5 + 0], x1 = feat[tt * 5 + 1],
                    x2 = feat[tt * 5 + 2], x3 = feat[tt * 5 + 3],
                    x4 = feat[tt * 5 + 4];
        float hs[16];
        const int c0 = g * 16;
        #pragma unroll
        for (int j = 0; j < 16; ++j) {
            int c = c0 + j;
            const float* w = cw + c * 5;
            float h = cb[c] + w[0]*x0 + w[1]*x1 + w[2]*x2 + w[3]*x3 + w[4]*x4;
            h1t[c * 64 + tt] = h;
            hs[j] = valid ? h : 0.f;
        }
        float mySum = 0.f, mySq = 0.f;
        #pragma unroll
        for (int j = 0; j < 16; ++j) {
            float s = hs[j];
            float q = hs[j] * hs[j];
            #pragma unroll
            for (int m = 1; m < 64; m <<= 1) {
                s += __shfl_xor(s, m, 64);
                q += __shfl_xor(q, m, 64);
            }
            if (tt == j) { mySum = s; mySq = q; }
        }
        if (tt < 16) {
            atomicAdd(ctrl + c0 + tt, mySum);
            atomicAdd(ctrl + 64 + c0 + tt, mySq);
        }
    }

    grid_sync(cnt0, nblk);

    // ---------- phase B: fold bn1 + relu + layer2 (LDS) + bn2 stats --------------
    if (tid < 64) {
        float invN = 1.f / (float)N;
        float su = __hip_atomic_load(ctrl + tid,      __ATOMIC_RELAXED, __HIP_MEMORY_SCOPE_AGENT);
        float sq = __hip_atomic_load(ctrl + 64 + tid, __ATOMIC_RELAXED, __HIP_MEMORY_SCOPE_AGENT);
        float mean = su * invN;
        float var  = sq * invN - mean * mean;
        float s = bn1_g[tid] * rsqrtf(var + 1e-5f);
        sc1[tid] = s;
        sh1[tid] = bn1_b[tid] - mean * s;
    }
    __syncthreads();

    float y[64];
    #pragma unroll
    for (int c = 0; c < 64; ++c)
        y[c] = fmaxf(h1t[c * 64 + tt] * sc1[c] + sh1[c], 0.f);

    {
        float hs[8];
        const int o0 = g * 8;
        #pragma unroll
        for (int j = 0; j < 8; ++j) {
            int o = o0 + j;
            const float* wo = w2 + o * 64;
            float acc = lb[o];
            #pragma unroll
            for (int c = 0; c < 64; ++c) acc += wo[c] * y[c];
            h2t[o * 65 + tt] = acc;
            hs[j] = valid ? acc : 0.f;
        }
        float mySum = 0.f, mySq = 0.f;
        #pragma unroll
        for (int j = 0; j < 8; ++j) {
            float s = hs[j];
            float q = hs[j] * hs[j];
            #pragma unroll
            for (int m = 1; m < 64; m <<= 1) {
                s += __shfl_xor(s, m, 64);
                q += __shfl_xor(q, m, 64);
            }
            if (tt == j) { mySum = s; mySq = q; }
        }
        if (tt < 8) {
            atomicAdd(ctrl + 128 + o0 + tt, mySum);
            atomicAdd(ctrl + 160 + o0 + tt, mySq);
        }
    }

    grid_sync(cnt1, nblk);

    // ---------- phase C: fold bn2 + relu + L2 normalize + store ------------------
    if (tid < 32) {
        float invN = 1.f / (float)N;
        float su = __hip_atomic_load(ctrl + 128 + tid, __ATOMIC_RELAXED, __HIP_MEMORY_SCOPE_AGENT);
        float sq = __hip_atomic_load(ctrl + 160 + tid, __ATOMIC_RELAXED, __HIP_MEMORY_SCOPE_AGENT);
        float mean = su * invN;
        float var  = sq * invN - mean * mean;
        float s = bn2_g[tid] * rsqrtf(var + 1e-5f);
        sc2[tid] = s;
        sh2[tid] = bn2_b[tid] - mean * s;
    }
    __syncthreads();

    {
        const int o0 = g * 8;
        float ss = 0.f;
        #pragma unroll
        for (int j = 0; j < 8; ++j) {
            int o = o0 + j;
            float v = fmaxf(h2t[o * 65 + tt] * sc2[o] + sh2[o], 0.f);
            h2t[o * 65 + tt] = v;
            ss += v * v;
        }
        ssqp[g * 64 + tt] = ss;
    }
    __syncthreads();
    if (g == 0) {
        float tot = ssqp[tt] + ssqp[64 + tt] + ssqp[128 + tt] + ssqp[192 + tt];
        linv[tt] = 1.f / fmaxf(sqrtf(tot), 1e-8f);
    }
    __syncthreads();

    const int nq = min(512, (N - t0) * 8);           // float4s this block owns
    float4* o4 = (float4*)(out + (size_t)t0 * 32);
    for (int q = tid; q < nq; q += TPB) {
        int tk = q >> 3;
        int oo = (q & 7) * 4;
        float iv = linv[tk];
        o4[q] = make_float4(h2t[(oo + 0) * 65 + tk] * iv,
                            h2t[(oo + 1) * 65 + tk] * iv,
                            h2t[(oo + 2) * 65 + tk] * iv,
                            h2t[(oo + 3) * 65 + tk] * iv);
    }
}

extern "C" void kernel_launch(void* const* d_in, const int* in_sizes, int n_in,
                              void* d_out, int out_size, void* d_ws, size_t ws_size,
                              hipStream_t stream) {
    const int*   labels     = (const int*)d_in[0];
    const float* fx         = (const float*)d_in[1];
    const float* fy         = (const float*)d_in[2];
    const int*   frame_idx  = (const int*)d_in[3];
    const int*   n_frames_p = (const int*)d_in[4];
    // d_in[5] = n_labels (derived from out_size instead)
    const float* conv_w = (const float*)d_in[6];
    const float* conv_b = (const float*)d_in[7];
    const float* bn1_g  = (const float*)d_in[8];
    const float* bn1_b  = (const float*)d_in[9];
    const float* lin_w  = (const float*)d_in[10];
    const float* lin_b  = (const float*)d_in[11];
    const float* bn2_g  = (const float*)d_in[12];
    const float* bn2_b  = (const float*)d_in[13];
    float* out = (float*)d_out;

    const int B = in_sizes[3];                       // 16
    const int P = in_sizes[0] / B;                   // 262144
    const int W = (int)(sqrt((double)P) + 0.5);      // 512 (square image)
    const int H = P / W;
    const int K = out_size / (B * 32);               // 1024
    const int N = B * K;                             // 16384

    int wlog = -1;
    if ((W & (W - 1)) == 0) { wlog = 0; while ((1 << wlog) < W) ++wlog; }

    // workspace layout (floats): ctrl[256] | partial[B*chunks*K*5]
    float* ctrl    = (float*)d_ws;
    float* partial = ctrl + 256;

    int chunks = 64;
    while (chunks > 1 &&
           ((size_t)B * chunks * K * 5 * sizeof(float) + 1024 > ws_size ||
            (P % (chunks * 4)) != 0))
        chunks >>= 1;
    while (P / chunks > 4096) chunks <<= 1;          // u64 fxy packing bound (2^15 scale)

    const int nblk = (N + 63) / 64;                  // 256 blocks; 38 KB LDS -> 4/CU capacity

    pool_kernel<<<B * chunks, TPB, (size_t)K * 16, stream>>>(
        labels, fx, fy, partial, ctrl, K, H, W, wlog, chunks);
    fused234_kernel<<<nblk, TPB, 0, stream>>>(
        partial, frame_idx, n_frames_p, conv_w, conv_b, bn1_g, bn1_b,
        lin_w, lin_b, bn2_g, bn2_b, ctrl, out, K, N, chunks);
}

// Round 11
// 159.188 us; speedup vs baseline: 1.0776x; 1.0776x over previous
//
#include <hip/hip_runtime.h>
#include <math.h>

#define TPB 256
#define FSCALE 16384.0f            // 2^14 fixed-point for fx/fy
#define INV_FSCALE (1.0f / 16384.0f)
#define FBIAS (1 << 17)            // per-add bias keeps packed fields positive
#define FCLAMP 7.0f                // |fx| clamp: 7*2^14 + 2^17 = 245760; *16384 < 2^32

// ctrl (floats): int barrier counters at [192] and [208]. BN stats now flow via
// statA/statB per-block partial tables (plain stores, no contended atomics).

// -------------------- pool: LDS int bins, 2 u64 atomics/pixel --------------------
__global__ void pool_kernel(const int* __restrict__ labels,
                            const float* __restrict__ fx,
                            const float* __restrict__ fy,
                            float* __restrict__ partial,
                            float* __restrict__ ctrl,
                            int K, int H, int W, int wlog, int chunks) {
    extern __shared__ unsigned long long sh[];   // geo[K] | fxy[K]
    unsigned long long* geo = sh;
    unsigned long long* fxy = sh + K;
    const int tid = threadIdx.x;

    if (blockIdx.x == 0 && tid < 224) ctrl[tid] = 0.f;   // barrier counters etc.

    for (int i = tid; i < K; i += TPB) { geo[i] = 0ull; fxy[i] = 0ull; }
    __syncthreads();

    const int P = H * W;
    const int b = blockIdx.x / chunks;
    const int chunk = blockIdx.x - b * chunks;
    const int chunkP = P / chunks;
    const size_t base = (size_t)b * P + (size_t)chunk * chunkP;
    const int4*   l4p  = (const int4*)(labels + base);
    const float4* fx4p = (const float4*)(fx + base);
    const float4* fy4p = (const float4*)(fy + base);
    const int nvec = chunkP >> 2;

    for (int v = tid; v < nvec; v += TPB) {
        int4   l4 = l4p[v];
        float4 f4 = fx4p[v];
        float4 g4 = fy4p[v];
        int p0 = chunk * chunkP + (v << 2);
        int   ls[4] = {l4.x, l4.y, l4.z, l4.w};
        float fs[4] = {f4.x, f4.y, f4.z, f4.w};
        float gs[4] = {g4.x, g4.y, g4.z, g4.w};
        #pragma unroll
        for (int s = 0; s < 4; ++s) {
            int p = p0 + s;
            int i, j;
            if (wlog >= 0) { i = p >> wlog; j = p & (W - 1); }
            else           { i = p / W;     j = p - i * W; }
            unsigned long long gadd = ((unsigned long long)i << 40)
                                    | ((unsigned long long)j << 16) | 1ull;
            int qx = __float2int_rn(fminf(fmaxf(fs[s], -FCLAMP), FCLAMP) * FSCALE) + FBIAS;
            int qy = __float2int_rn(fminf(fmaxf(gs[s], -FCLAMP), FCLAMP) * FSCALE) + FBIAS;
            unsigned long long fadd = ((unsigned long long)(unsigned int)qx << 32)
                                    | (unsigned long long)(unsigned int)qy;
            atomicAdd(&geo[ls[s]], gadd);
            atomicAdd(&fxy[ls[s]], fadd);
        }
    }
    __syncthreads();

    const float sx = 2.f / (float)(H - 1);           // xx varies along dim 2 (i)
    const float sy = 2.f / (float)(W - 1);           // yy varies along dim 3 (j)
    float* outp = partial + (size_t)blockIdx.x * K * 5;
    for (int k = tid; k < K; k += TPB) {
        unsigned long long g = geo[k];
        unsigned long long ff = fxy[k];
        unsigned int ci = (unsigned int)(g & 0xFFFFull);
        float cnt = (float)ci;
        float sj  = (float)(unsigned int)((g >> 16) & 0xFFFFFFull);
        float si  = (float)(unsigned int)(g >> 40);
        long long cbias = (long long)ci << 17;
        float* p = outp + k * 5;
        p[0] = (float)((long long)(ff >> 32) - cbias) * INV_FSCALE;           // sum fx
        p[1] = (float)((long long)(ff & 0xFFFFFFFFull) - cbias) * INV_FSCALE; // sum fy
        p[2] = sx * si - cnt;                        // sum xx
        p[3] = sy * sj - cnt;                        // sum yy
        p[4] = cnt;                                  // count
    }
}

// -------------------- grid barrier: release arrival, relaxed polls, one acquire --
// Round-10 proven-correct protocol. RELEASE makes the block's plain stores
// (statA/statB rows) visible; single ACQUIRE after the poll orders the block's
// subsequent plain reads. Lane-0-only cache ops are CU/XCD-wide; __syncthreads
// extends the ordering to all the block's waves.
__device__ __forceinline__ void grid_sync(int* cnt, int nblk) {
    __syncthreads();
    if (threadIdx.x == 0) {
        __hip_atomic_fetch_add(cnt, 1, __ATOMIC_RELEASE, __HIP_MEMORY_SCOPE_AGENT);
        while (__hip_atomic_load(cnt, __ATOMIC_RELAXED, __HIP_MEMORY_SCOPE_AGENT) < nblk)
            __builtin_amdgcn_s_sleep(8);
        __hip_atomic_load(cnt, __ATOMIC_ACQUIRE, __HIP_MEMORY_SCOPE_AGENT);
    }
    __syncthreads();
}

// -------------------- K2: reduce+layer1 | bn1+layer2 | bn2+normalize -------------
// 256 blocks x 256 threads; block owns 64 tokens; h1/h2 in LDS only.
// BN stats: per-block partial rows (plain stores) -> barrier -> every block
// redundantly reduces the table (deterministic order => identical results).
__global__ __launch_bounds__(TPB)
void fused234_kernel(const float* __restrict__ partial,
                     const int* __restrict__ frame_idx,
                     const int* __restrict__ n_frames_p,
                     const float* __restrict__ conv_w,
                     const float* __restrict__ conv_b,
                     const float* __restrict__ bn1_g,
                     const float* __restrict__ bn1_b,
                     const float* __restrict__ lin_w,
                     const float* __restrict__ lin_b,
                     const float* __restrict__ bn2_g,
                     const float* __restrict__ bn2_b,
                     float* __restrict__ ctrl,
                     float* __restrict__ statA,   // [nblk][128]: 64 sum | 64 sumsq
                     float* __restrict__ statB,   // [nblk][64]: 32 sum | 32 sumsq
                     float* __restrict__ out,
                     int K, int N, int chunks) {
    __shared__ float red[320], feat[320], cw[320], cb[64];
    __shared__ float h1t[64 * 64];                   // [c][tt]
    __shared__ float w2[2048], lb[32];
    __shared__ float sc1[64], sh1[64], sc2[32], sh2[32];
    __shared__ float h2t[32 * 65];                   // [o][tt], padded
    __shared__ float ssqp[4 * 64], linv[64];

    const int tid = threadIdx.x;
    const int nblk = gridDim.x;
    const int bid = blockIdx.x;
    int* cnt0 = (int*)(ctrl + 192);
    int* cnt1 = (int*)(ctrl + 208);

    // stage weights (overlaps phase A loads)
    for (int i = tid; i < 320; i += TPB) cw[i] = conv_w[i];
    if (tid < 64) cb[tid] = conv_b[tid];
    for (int i = tid; i < 2048; i += TPB) w2[i] = lin_w[i];
    if (tid < 32) lb[tid] = lin_b[tid];

    // ---------- phase A: reduce slabs + mean + layer1 (LDS) + bn1 partials -------
    const int t0 = bid * 64;
    const int b  = t0 / K;                           // 64 | K -> one batch per block
    const int k0 = t0 - b * K;

    float acc0 = 0.f, acc1 = 0.f;
    const float* pb = partial + ((size_t)b * chunks * K + k0) * 5;
    for (int ch = 0; ch < chunks; ++ch) {            // chunks = 16: short, pipelined
        const float* pc = pb + (size_t)ch * K * 5;
        acc0 += pc[tid];
        if (tid < 64) acc1 += pc[256 + tid];
    }
    red[tid] = acc0;
    if (tid < 64) red[256 + tid] = acc1;
    __syncthreads();

    const int g  = tid >> 6;
    const int tt = tid & 63;
    const int t  = t0 + tt;
    const bool valid = t < N;
    if (g == 0) {
        const float* r = red + tt * 5;
        float inv = 1.f / fmaxf(r[4], 1.f);
        float invnf = 1.f / (float)(n_frames_p[0] - 1);
        feat[tt * 5 + 0] = valid ? (float)frame_idx[b] * invnf : 0.f;
        feat[tt * 5 + 1] = r[0] * inv;
        feat[tt * 5 + 2] = r[1] * inv;
        feat[tt * 5 + 3] = r[2] * inv;
        feat[tt * 5 + 4] = r[3] * inv;
    }
    __syncthreads();

    {
        const float x0 = feat[tt * 5 + 0], x1 = feat[tt * 5 + 1],
                    x2 = feat[tt * 5 + 2], x3 = feat[tt * 5 + 3],
                    x4 = feat[tt * 5 + 4];
        float hs[16];
        const int c0 = g * 16;
        #pragma unroll
        for (int j = 0; j < 16; ++j) {
            int c = c0 + j;
            const float* w = cw + c * 5;
            float h = cb[c] + w[0]*x0 + w[1]*x1 + w[2]*x2 + w[3]*x3 + w[4]*x4;
            h1t[c * 64 + tt] = h;
            hs[j] = valid ? h : 0.f;
        }
        float mySum = 0.f, mySq = 0.f;
        #pragma unroll
        for (int j = 0; j < 16; ++j) {
            float s = hs[j];
            float q = hs[j] * hs[j];
            #pragma unroll
            for (int m = 1; m < 64; m <<= 1) {
                s += __shfl_xor(s, m, 64);
                q += __shfl_xor(q, m, 64);
            }
            if (tt == j) { mySum = s; mySq = q; }
        }
        if (tt < 16) {                               // plain stores: zero contention
            statA[(size_t)bid * 128 + c0 + tt] = mySum;
            statA[(size_t)bid * 128 + 64 + c0 + tt] = mySq;
        }
    }

    grid_sync(cnt0, nblk);

    // ---------- phase B: redundant statA reduce -> bn1 fold + layer2 + bn2 partials
    {
        const int col  = tid & 127;                  // 0..63 sums, 64..127 sumsq
        const int half = tid >> 7;
        float a = 0.f;
        const float* base = statA + (size_t)half * 128 * 128 + col;
        for (int r = 0; r < 128; ++r)
            a += base[(size_t)r * 128];
        red[tid] = a;
    }
    __syncthreads();
    if (tid < 64) {
        float su = red[tid] + red[128 + tid];
        float sq = red[64 + tid] + red[192 + tid];
        float invN = 1.f / (float)N;
        float mean = su * invN;
        float var  = sq * invN - mean * mean;
        float s = bn1_g[tid] * rsqrtf(var + 1e-5f);
        sc1[tid] = s;
        sh1[tid] = bn1_b[tid] - mean * s;
    }
    __syncthreads();

    float y[64];
    #pragma unroll
    for (int c = 0; c < 64; ++c)
        y[c] = fmaxf(h1t[c * 64 + tt] * sc1[c] + sh1[c], 0.f);

    {
        float hs[8];
        const int o0 = g * 8;
        #pragma unroll
        for (int j = 0; j < 8; ++j) {
            int o = o0 + j;
            const float* wo = w2 + o * 64;
            float acc = lb[o];
            #pragma unroll
            for (int c = 0; c < 64; ++c) acc += wo[c] * y[c];
            h2t[o * 65 + tt] = acc;
            hs[j] = valid ? acc : 0.f;
        }
        float mySum = 0.f, mySq = 0.f;
        #pragma unroll
        for (int j = 0; j < 8; ++j) {
            float s = hs[j];
            float q = hs[j] * hs[j];
            #pragma unroll
            for (int m = 1; m < 64; m <<= 1) {
                s += __shfl_xor(s, m, 64);
                q += __shfl_xor(q, m, 64);
            }
            if (tt == j) { mySum = s; mySq = q; }
        }
        if (tt < 8) {
            statB[(size_t)bid * 64 + o0 + tt] = mySum;
            statB[(size_t)bid * 64 + 32 + o0 + tt] = mySq;
        }
    }

    grid_sync(cnt1, nblk);

    // ---------- phase C: redundant statB reduce -> bn2 fold + normalize + store --
    {
        const int col = tid & 63;                    // 0..31 sums, 32..63 sumsq
        const int qr  = tid >> 6;
        float a = 0.f;
        const float* base = statB + (size_t)qr * 64 * 64 + col;
        for (int r = 0; r < 64; ++r)
            a += base[(size_t)r * 64];
        red[tid] = a;
    }
    __syncthreads();
    if (tid < 32) {
        float su = red[tid] + red[64 + tid] + red[128 + tid] + red[192 + tid];
        float sq = red[32 + tid] + red[96 + tid] + red[160 + tid] + red[224 + tid];
        float invN = 1.f / (float)N;
        float mean = su * invN;
        float var  = sq * invN - mean * mean;
        float s = bn2_g[tid] * rsqrtf(var + 1e-5f);
        sc2[tid] = s;
        sh2[tid] = bn2_b[tid] - mean * s;
    }
    __syncthreads();

    {
        const int o0 = g * 8;
        float ss = 0.f;
        #pragma unroll
        for (int j = 0; j < 8; ++j) {
            int o = o0 + j;
            float v = fmaxf(h2t[o * 65 + tt] * sc2[o] + sh2[o], 0.f);
            h2t[o * 65 + tt] = v;
            ss += v * v;
        }
        ssqp[g * 64 + tt] = ss;
    }
    __syncthreads();
    if (g == 0) {
        float tot = ssqp[tt] + ssqp[64 + tt] + ssqp[128 + tt] + ssqp[192 + tt];
        linv[tt] = 1.f / fmaxf(sqrtf(tot), 1e-8f);
    }
    __syncthreads();

    const int nq = min(512, (N - t0) * 8);           // float4s this block owns
    float4* o4 = (float4*)(out + (size_t)t0 * 32);
    for (int q = tid; q < nq; q += TPB) {
        int tk = q >> 3;
        int oo = (q & 7) * 4;
        float iv = linv[tk];
        o4[q] = make_float4(h2t[(oo + 0) * 65 + tk] * iv,
                            h2t[(oo + 1) * 65 + tk] * iv,
                            h2t[(oo + 2) * 65 + tk] * iv,
                            h2t[(oo + 3) * 65 + tk] * iv);
    }
}

extern "C" void kernel_launch(void* const* d_in, const int* in_sizes, int n_in,
                              void* d_out, int out_size, void* d_ws, size_t ws_size,
                              hipStream_t stream) {
    const int*   labels     = (const int*)d_in[0];
    const float* fx         = (const float*)d_in[1];
    const float* fy         = (const float*)d_in[2];
    const int*   frame_idx  = (const int*)d_in[3];
    const int*   n_frames_p = (const int*)d_in[4];
    // d_in[5] = n_labels (derived from out_size instead)
    const float* conv_w = (const float*)d_in[6];
    const float* conv_b = (const float*)d_in[7];
    const float* bn1_g  = (const float*)d_in[8];
    const float* bn1_b  = (const float*)d_in[9];
    const float* lin_w  = (const float*)d_in[10];
    const float* lin_b  = (const float*)d_in[11];
    const float* bn2_g  = (const float*)d_in[12];
    const float* bn2_b  = (const float*)d_in[13];
    float* out = (float*)d_out;

    const int B = in_sizes[3];                       // 16
    const int P = in_sizes[0] / B;                   // 262144
    const int W = (int)(sqrt((double)P) + 0.5);      // 512 (square image)
    const int H = P / W;
    const int K = out_size / (B * 32);               // 1024
    const int N = B * K;                             // 16384

    int wlog = -1;
    if ((W & (W - 1)) == 0) { wlog = 0; while ((1 << wlog) < W) ++wlog; }

    const int nblk = (N + 63) / 64;                  // 256 blocks, co-resident

    // workspace (floats): ctrl[256] | statA[nblk*128] | statB[nblk*64] | partial
    float* ctrl    = (float*)d_ws;
    float* statA   = ctrl + 256;
    float* statB   = statA + (size_t)nblk * 128;
    float* partial = statB + (size_t)nblk * 64;

    int chunks = 16;
    while (chunks > 1 && (P % (chunks * 4)) != 0) chunks >>= 1;
    while (P / chunks > 16384) chunks <<= 1;         // u64 fxy packing bound (2^14 scale)

    pool_kernel<<<B * chunks, TPB, (size_t)K * 16, stream>>>(
        labels, fx, fy, partial, ctrl, K, H, W, wlog, chunks);
    fused234_kernel<<<nblk, TPB, 0, stream>>>(
        partial, frame_idx, n_frames_p, conv_w, conv_b, bn1_g, bn1_b,
        lin_w, lin_b, bn2_g, bn2_b, ctrl, statA, statB, out, K, N, chunks);
}